// Round 3
// baseline (366.015 us; speedup 1.0000x reference)
//
#include <hip/hip_runtime.h>
#include <math.h>

#define IN_DIM 28
#define BOND   10
#define OUT_D  10
#define BLOCK  256
#define SPT    2                 // samples per thread
#define H0_STRIDE 11             // odd stride -> conflict-free h0 slots

// One thread = SPT samples. Weights in LDS, read as ds_read_b128 broadcasts
// (all lanes same addr, immediate offsets -> zero address VALU). Each weight
// read now feeds 4*SPT FMAs, halving the per-sample LDS-pipe load vs R2.
__global__ __launch_bounds__(BLOCK) void tn_kernel(
    const float* __restrict__ x,     // [N, 56]
    const float* __restrict__ t0,    // [28,10]
    const float* __restrict__ t1,    // [28,10,10]
    const float* __restrict__ bias,  // [10]
    float* __restrict__ out,         // [N,10]
    int n_total)
{
    __shared__ __align__(16) float lt0[IN_DIM * BOND];            // 280, [i][b]
    __shared__ __align__(16) float lt1[BOND * IN_DIM * OUT_D];    // 2800, [b][j][o]
    __shared__ float lbias[OUT_D];
    __shared__ float lh0[SPT * BLOCK * H0_STRIDE];                // h0 spill

    const int tid = threadIdx.x;

    // ---- cooperative staging ----
    for (int idx = tid; idx < IN_DIM * BOND; idx += BLOCK)
        lt0[idx] = t0[idx];
    for (int idx = tid; idx < BOND * IN_DIM * OUT_D; idx += BLOCK) {
        const int b = idx / (IN_DIM * OUT_D);
        const int r = idx - b * (IN_DIM * OUT_D);
        const int j = r / OUT_D;
        const int o = r - j * OUT_D;
        lt1[idx] = t1[(j * BOND + b) * OUT_D + o];   // [j][b][o] -> [b][j][o]
    }
    if (tid < OUT_D) lbias[tid] = bias[tid];

    const int base = blockIdx.x * (BLOCK * SPT);
    const int nA = base + tid;            // sample A
    const int nB = base + BLOCK + tid;    // sample B

    // ---- load both samples' 56 floats (14 float4 each, rows 16-aligned) ----
    float4 qA[14], qB[14];
    {
        const float4* __restrict__ rA =
            reinterpret_cast<const float4*>(x + (size_t)nA * (2 * IN_DIM));
        const float4* __restrict__ rB =
            reinterpret_cast<const float4*>(x + (size_t)nB * (2 * IN_DIM));
#pragma unroll
        for (int k = 0; k < 14; ++k) qA[k] = rA[k];
#pragma unroll
        for (int k = 0; k < 14; ++k) qB[k] = rB[k];
    }

    __syncthreads();

    // unpack to compile-time-indexed register arrays
    float eA[2 * IN_DIM], eB[2 * IN_DIM];
#pragma unroll
    for (int k = 0; k < 14; ++k) {
        eA[4 * k + 0] = qA[k].x; eA[4 * k + 1] = qA[k].y;
        eA[4 * k + 2] = qA[k].z; eA[4 * k + 3] = qA[k].w;
        eB[4 * k + 0] = qB[k].x; eB[4 * k + 1] = qB[k].y;
        eB[4 * k + 2] = qB[k].z; eB[4 * k + 3] = qB[k].w;
    }

    // ---- h0[b] = sum_i x0[i]*t0[i][b]; one b128 read feeds both samples ----
    float hA[BOND], hB[BOND];
#pragma unroll
    for (int b = 0; b < BOND; ++b) { hA[b] = 0.0f; hB[b] = 0.0f; }
    {
        const float4* __restrict__ w0 = reinterpret_cast<const float4*>(lt0);
#pragma unroll
        for (int c = 0; c < 70; ++c) {
            const float4 w = w0[c];
            const int f = 4 * c;
#define H0_STEP(K, WK)                                                   \
            hA[(f + K) % 10] = fmaf(eA[(f + K) / 10], WK, hA[(f + K) % 10]); \
            hB[(f + K) % 10] = fmaf(eB[(f + K) / 10], WK, hB[(f + K) % 10]);
            H0_STEP(0, w.x) H0_STEP(1, w.y) H0_STEP(2, w.z) H0_STEP(3, w.w)
#undef H0_STEP
        }
    }
    // spill h0 (runtime-b access in rolled loop); stride 11 -> conflict-free
#pragma unroll
    for (int b = 0; b < BOND; ++b) {
        lh0[(0 * BLOCK + tid) * H0_STRIDE + b] = hA[b];
        lh0[(1 * BLOCK + tid) * H0_STRIDE + b] = hB[b];
    }

    // ---- c[o] = bias[o] + sum_b h0[b] * (sum_j x1[j]*t1'[b][j][o]) ----
    float aA[OUT_D], aB[OUT_D];
#pragma unroll
    for (int o = 0; o < OUT_D; ++o) { aA[o] = lbias[o]; aB[o] = lbias[o]; }

#pragma unroll 1   // rolled: body ~6 KB, stays in L1I
    for (int b = 0; b < BOND; ++b) {
        const float hbA = lh0[(0 * BLOCK + tid) * H0_STRIDE + b];
        const float hbB = lh0[(1 * BLOCK + tid) * H0_STRIDE + b];
        const float4* __restrict__ wb =
            reinterpret_cast<const float4*>(&lt1[b * (IN_DIM * OUT_D)]);
        float gA[OUT_D], gB[OUT_D];
#pragma unroll
        for (int o = 0; o < OUT_D; ++o) { gA[o] = 0.0f; gB[o] = 0.0f; }
#pragma unroll
        for (int c = 0; c < 70; ++c) {
            const float4 w = wb[c];
            const int f = 4 * c;
#define H1_STEP(K, WK)                                                       \
            gA[(f + K) % 10] = fmaf(eA[28 + (f + K) / 10], WK, gA[(f + K) % 10]); \
            gB[(f + K) % 10] = fmaf(eB[28 + (f + K) / 10], WK, gB[(f + K) % 10]);
            H1_STEP(0, w.x) H1_STEP(1, w.y) H1_STEP(2, w.z) H1_STEP(3, w.w)
#undef H1_STEP
        }
#pragma unroll
        for (int o = 0; o < OUT_D; ++o) {
            aA[o] = fmaf(hbA, gA[o], aA[o]);
            aB[o] = fmaf(hbB, gB[o], aB[o]);
        }
    }

    // ---- sigmoid + store (rows 40 B, 8-aligned -> float2 stores) ----
    if (nA < n_total) {
        float2* __restrict__ op =
            reinterpret_cast<float2*>(out + (size_t)nA * OUT_D);
#pragma unroll
        for (int o = 0; o < OUT_D; o += 2) {
            float2 r;
            r.x = 1.0f / (1.0f + __expf(-aA[o]));
            r.y = 1.0f / (1.0f + __expf(-aA[o + 1]));
            op[o >> 1] = r;
        }
    }
    if (nB < n_total) {
        float2* __restrict__ op =
            reinterpret_cast<float2*>(out + (size_t)nB * OUT_D);
#pragma unroll
        for (int o = 0; o < OUT_D; o += 2) {
            float2 r;
            r.x = 1.0f / (1.0f + __expf(-aB[o]));
            r.y = 1.0f / (1.0f + __expf(-aB[o + 1]));
            op[o >> 1] = r;
        }
    }
}

extern "C" void kernel_launch(void* const* d_in, const int* in_sizes, int n_in,
                              void* d_out, int out_size, void* d_ws, size_t ws_size,
                              hipStream_t stream) {
    const float* x    = (const float*)d_in[0];
    const float* t0   = (const float*)d_in[1];
    const float* t1   = (const float*)d_in[2];
    const float* bias = (const float*)d_in[3];
    float* out        = (float*)d_out;

    const int n_total = in_sizes[0] / (2 * IN_DIM);
    const int grid = (n_total + BLOCK * SPT - 1) / (BLOCK * SPT);
    tn_kernel<<<grid, BLOCK, 0, stream>>>(x, t0, t1, bias, out, n_total);
}